// Round 1
// baseline (1256.659 us; speedup 1.0000x reference)
//
#include <hip/hip_runtime.h>
#include <hip/hip_bf16.h>

// Problem: B=32, T=4096, DEC=1024, ENC=1024, ATTN=512, K=10
// out = [context (32*1024) | align (32*4096)] fp32
//
// Pipeline:
//  prep: wv->bf16, qb2[b,a] = q@WQ^T + bias + convb@WU^T, A0/A1/A2[a] = conv taps @ WU^T
//  gemm: score[b,t] = fc_w . tanh(value@WV^T + qb2 + 3-tap(la)) ; sig = sigmoid; bsum[b] += sig
//  align = sig / bsum ; context = sum_t align * value (atomic accumulate)

typedef __attribute__((ext_vector_type(8))) short bf8_t;
typedef __attribute__((ext_vector_type(4))) float f4_t;

__device__ inline unsigned short f2bf(float f) {
    union { float f; unsigned u; } v; v.f = f;
    unsigned u = v.u + 0x7fffu + ((v.u >> 16) & 1u);  // RNE
    return (unsigned short)(u >> 16);
}

__global__ void k_wv2bf(const float* __restrict__ wv, unsigned short* __restrict__ out) {
    int i = blockIdx.x * 256 + threadIdx.x;           // 131072 threads, 4 elems each
    float4 v = ((const float4*)wv)[i];
    uint2 p;
    p.x = (unsigned)f2bf(v.x) | ((unsigned)f2bf(v.y) << 16);
    p.y = (unsigned)f2bf(v.z) | ((unsigned)f2bf(v.w) << 16);
    ((uint2*)out)[i] = p;
}

__global__ void k_qb2(const float* __restrict__ query, const float* __restrict__ WQ,
                      const float* __restrict__ bias, const float* __restrict__ convb,
                      const float* __restrict__ WU, float* __restrict__ qb2) {
    __shared__ float qs[1024];
    int b = blockIdx.x;
    for (int d = threadIdx.x; d < 1024; d += 256) qs[d] = query[b * 1024 + d];
    __syncthreads();
    for (int a = threadIdx.x; a < 512; a += 256) {
        float s = bias[a];
        for (int k = 0; k < 10; k++) s += convb[k] * WU[a * 10 + k];
        const float4* wq = (const float4*)(WQ + a * 1024);
        const float4* q4 = (const float4*)qs;
        float acc = 0.f;
        for (int d = 0; d < 256; d++) {
            float4 w = wq[d]; float4 q = q4[d];
            acc += w.x * q.x + w.y * q.y + w.z * q.z + w.w * q.w;
        }
        qb2[b * 512 + a] = s + acc;
    }
}

__global__ void k_a012(const float* __restrict__ cw, const float* __restrict__ WU,
                       float* __restrict__ a012) {
    int a = blockIdx.x * 256 + threadIdx.x;
    if (a < 512) {
        float s0 = 0.f, s1 = 0.f, s2 = 0.f;
        for (int k = 0; k < 10; k++) {
            float w = WU[a * 10 + k];
            s0 += cw[k * 3 + 0] * w;   // tap on la[t-1]
            s1 += cw[k * 3 + 1] * w;   // tap on la[t]
            s2 += cw[k * 3 + 2] * w;   // tap on la[t+1]
        }
        a012[a] = s0; a012[512 + a] = s1; a012[1024 + a] = s2;
    }
}

// GEMM: grid 1024 blocks, 512 threads (8 waves). Block tile 128 rows x 512 cols, BK=32.
// Wave tile 64x128 (4x8 of 16x16x32 MFMAs). value fp32 -> bf16 into LDS; WV pre-bf16.
__global__ __launch_bounds__(512, 2) void k_gemm(
    const float* __restrict__ value, const unsigned short* __restrict__ wvbf,
    const float* __restrict__ qb2, const float* __restrict__ a012,
    const float* __restrict__ fcw, const float* __restrict__ la,
    float* __restrict__ sigbuf, float* __restrict__ bsum) {
    __shared__ unsigned short As[128][48];   // 12 KB (stride 48 = 96B, 16B-aligned rows)
    __shared__ unsigned short Bs[512][48];   // 48 KB
    __shared__ float rowLa[3][128];
    __shared__ float scoreRed[128][4];

    const int tid = threadIdx.x;
    const int lane = tid & 63;
    const int wave = tid >> 6;
    const int wm = (wave & 1) * 64;          // row half
    const int wn = (wave >> 1) * 128;        // col quarter
    const int rowBase = blockIdx.x * 128;
    const int bIdx = blockIdx.x >> 5;        // 32 blocks per batch

    f4_t acc[4][8];
#pragma unroll
    for (int i = 0; i < 4; i++)
#pragma unroll
        for (int j = 0; j < 8; j++) acc[i][j] = (f4_t)0.0f;

    const int ar = tid >> 2;                 // A staging: 4 threads/row
    const int ac = (tid & 3) * 8;
    const float4* aptr = (const float4*)(value + (size_t)(rowBase + ar) * 1024 + ac);
    const int br = tid >> 2;                 // B staging: 4 passes of 128 rows
    const int bc = (tid & 3) * 8;

    const int koff = (lane >> 4) * 8;
    const int am = wm + (lane & 15);

    for (int kk = 0; kk < 32; ++kk) {
        const int k0 = kk * 32;
        float4 av0 = aptr[(k0 >> 2)];
        float4 av1 = aptr[(k0 >> 2) + 1];
        uint4 bv[4];
#pragma unroll
        for (int p = 0; p < 4; p++)
            bv[p] = *(const uint4*)(wvbf + (size_t)(p * 128 + br) * 1024 + k0 + bc);

        __syncthreads();
        uint4 ap;
        ap.x = (unsigned)f2bf(av0.x) | ((unsigned)f2bf(av0.y) << 16);
        ap.y = (unsigned)f2bf(av0.z) | ((unsigned)f2bf(av0.w) << 16);
        ap.z = (unsigned)f2bf(av1.x) | ((unsigned)f2bf(av1.y) << 16);
        ap.w = (unsigned)f2bf(av1.z) | ((unsigned)f2bf(av1.w) << 16);
        *(uint4*)&As[ar][ac] = ap;
#pragma unroll
        for (int p = 0; p < 4; p++) *(uint4*)&Bs[p * 128 + br][bc] = bv[p];
        __syncthreads();

        bf8_t af[4];
#pragma unroll
        for (int i = 0; i < 4; i++) af[i] = *(const bf8_t*)&As[am + i * 16][koff];
#pragma unroll
        for (int j = 0; j < 8; j++) {
            bf8_t bfv = *(const bf8_t*)&Bs[wn + j * 16 + (lane & 15)][koff];
#pragma unroll
            for (int i = 0; i < 4; i++)
                acc[i][j] = __builtin_amdgcn_mfma_f32_16x16x32_bf16(af[i], bfv, acc[i][j], 0, 0, 0);
        }
    }

    // epilogue: row conv taps
    if (tid < 128) {
        int grow = rowBase + tid;
        int t = grow & 4095;
        rowLa[0][tid] = (t == 0) ? 0.f : la[grow - 1];
        rowLa[1][tid] = la[grow];
        rowLa[2][tid] = (t == 4095) ? 0.f : la[grow + 1];
    }
    float qv[8], c0[8], c1[8], c2[8], fv[8];
#pragma unroll
    for (int j = 0; j < 8; j++) {
        int a = wn + j * 16 + (lane & 15);
        qv[j] = qb2[bIdx * 512 + a];
        c0[j] = a012[a]; c1[j] = a012[512 + a]; c2[j] = a012[1024 + a];
        fv[j] = fcw[a];
    }
    __syncthreads();

    const int q4 = lane >> 4;
#pragma unroll
    for (int i = 0; i < 4; i++) {
#pragma unroll
        for (int r = 0; r < 4; r++) {
            int row = wm + i * 16 + q4 * 4 + r;   // C/D: col=lane&15, row=(lane>>4)*4+reg
            float lm = rowLa[0][row], l0 = rowLa[1][row], lp = rowLa[2][row];
            float s = 0.f;
#pragma unroll
            for (int j = 0; j < 8; j++) {
                float x = acc[i][j][r] + qv[j] + lm * c0[j] + l0 * c1[j] + lp * c2[j];
                float e = __expf(2.f * x);
                s += fv[j] * (1.f - 2.f / (e + 1.f));   // tanh(x)*fc_w
            }
            s += __shfl_xor(s, 1); s += __shfl_xor(s, 2);
            s += __shfl_xor(s, 4); s += __shfl_xor(s, 8);
            if ((lane & 15) == 0) scoreRed[row][wave >> 1] = s;
        }
    }
    __syncthreads();

    if (tid < 128) {
        float full = scoreRed[tid][0] + scoreRed[tid][1] + scoreRed[tid][2] + scoreRed[tid][3];
        float sg = 1.f / (1.f + __expf(-full));
        sigbuf[rowBase + tid] = sg;
        float w = sg;
        w += __shfl_xor(w, 1); w += __shfl_xor(w, 2); w += __shfl_xor(w, 4);
        w += __shfl_xor(w, 8); w += __shfl_xor(w, 16); w += __shfl_xor(w, 32);
        if (lane == 0) atomicAdd(&bsum[bIdx], w);
    }
}

__global__ void k_align(const float* __restrict__ sig, const float* __restrict__ bsum,
                        float* __restrict__ out) {
    int i = blockIdx.x * 256 + threadIdx.x;
    out[i] = sig[i] / bsum[i >> 12];
}

__global__ __launch_bounds__(256) void k_ctx(const float* __restrict__ value,
                                             const float* __restrict__ alignw,
                                             float* __restrict__ ctx) {
    int e = blockIdx.x * 256 + threadIdx.x;
    int b = blockIdx.z;
    int t0 = blockIdx.y * 512;
    const float* vp = value + (size_t)(b * 4096 + t0) * 1024 + e;
    const float* wp = alignw + b * 4096 + t0;
    float a0 = 0.f, a1 = 0.f, a2 = 0.f, a3 = 0.f;
    for (int t = 0; t < 512; t += 4) {
        a0 += wp[t + 0] * vp[(size_t)(t + 0) * 1024];
        a1 += wp[t + 1] * vp[(size_t)(t + 1) * 1024];
        a2 += wp[t + 2] * vp[(size_t)(t + 2) * 1024];
        a3 += wp[t + 3] * vp[(size_t)(t + 3) * 1024];
    }
    atomicAdd(&ctx[b * 1024 + e], a0 + a1 + a2 + a3);
}

extern "C" void kernel_launch(void* const* d_in, const int* in_sizes, int n_in,
                              void* d_out, int out_size, void* d_ws, size_t ws_size,
                              hipStream_t stream) {
    const float* query = (const float*)d_in[0];
    const float* value = (const float*)d_in[1];
    const float* la    = (const float*)d_in[2];
    const float* convw = (const float*)d_in[3];
    const float* convb = (const float*)d_in[4];
    const float* WQ    = (const float*)d_in[5];
    const float* WV    = (const float*)d_in[6];
    const float* WU    = (const float*)d_in[7];
    const float* bias  = (const float*)d_in[8];
    const float* fcw   = (const float*)d_in[9];
    float* out = (float*)d_out;   // [context 32*1024 | align 32*4096]

    char* ws = (char*)d_ws;
    float* sigbuf = (float*)ws;                               // 131072 f
    float* qb2    = (float*)(ws + 524288);                    // 16384 f
    float* a012   = (float*)(ws + 589824);                    // 1536 f
    float* bsum   = (float*)(ws + 595968);                    // 32 f
    unsigned short* wvbf = (unsigned short*)(ws + 596096);    // 524288 bf16 (1 MB)

    hipMemsetAsync(bsum, 0, 32 * sizeof(float), stream);
    hipMemsetAsync(out, 0, 32 * 1024 * sizeof(float), stream);

    k_wv2bf<<<512, 256, 0, stream>>>(WV, wvbf);
    k_qb2<<<32, 256, 0, stream>>>(query, WQ, bias, convb, WU, qb2);
    k_a012<<<2, 256, 0, stream>>>(convw, WU, a012);
    k_gemm<<<1024, 512, 0, stream>>>(value, wvbf, qb2, a012, fcw, la, sigbuf, bsum);
    k_align<<<512, 256, 0, stream>>>(sigbuf, bsum, out + 32768);
    k_ctx<<<dim3(4, 8, 32), 256, 0, stream>>>(value, out + 32768, out);
}